// Round 1
// baseline (7959.897 us; speedup 1.0000x reference)
//
#include <hip/hip_runtime.h>
#include <math.h>

// Problem constants (B=4, T=512, H=2048, V=32000)
#define BATCH 4
#define TSEQ 512
#define MTOK 2048          // B*T
#define HDIM 2048
#define VOCAB 32000
#define NCHUNK 500         // VOCAB / 64
#define IGNORE_INDEX (-100)
#define BETA 0.1f

typedef __attribute__((ext_vector_type(4))) float floatx4;
typedef __attribute__((ext_vector_type(8))) short short8;
typedef __attribute__((ext_vector_type(8))) unsigned short ushort8;

// ---------------------------------------------------------------- utilities
__device__ __forceinline__ unsigned short f2bf(float f) {
    unsigned int u = __float_as_uint(f);
    u += 0x7fffu + ((u >> 16) & 1u);   // RNE
    return (unsigned short)(u >> 16);
}

__device__ __forceinline__ void async_copy16(const unsigned short* g, unsigned short* l) {
    __builtin_amdgcn_global_load_lds(
        (const __attribute__((address_space(1))) void*)g,
        (__attribute__((address_space(3))) void*)l, 16, 0, 0);
}

// ------------------------------------------------------------ fp32 -> bf16
// n must be a multiple of 2048; grid = n/2048, block = 256, 8 elts/thread
__global__ __launch_bounds__(256) void cvt_bf16_kernel(
        const float* __restrict__ src, unsigned short* __restrict__ dst) {
    size_t i = (size_t)blockIdx.x * 256 + threadIdx.x;
    const floatx4* s = (const floatx4*)src + i * 2;
    floatx4 a = s[0];
    floatx4 b = s[1];
    ushort8 o;
    o[0] = f2bf(a[0]); o[1] = f2bf(a[1]); o[2] = f2bf(a[2]); o[3] = f2bf(a[3]);
    o[4] = f2bf(b[0]); o[5] = f2bf(b[1]); o[6] = f2bf(b[2]); o[7] = f2bf(b[3]);
    *((ushort8*)dst + i) = o;
}

// ------------------------------------------------------- GEMM + fused LSE
// C = Xb (M x H) * Wb^T (V x H)  -> per-token (max, sumexp) per 64-vocab chunk
// grid = (M/128, V/128), block = 256 (4 waves, each 64x64 via 4x4 MFMA 16x16x32)
#define BK 64
__global__ __launch_bounds__(256, 2) void gemm_lse_kernel(
        const unsigned short* __restrict__ Xb,   // M x H bf16
        const unsigned short* __restrict__ Wb,   // V x H bf16
        const int* __restrict__ y,               // M labels
        float* __restrict__ pmax,                // M x NCHUNK
        float* __restrict__ psum,                // M x NCHUNK
        float* __restrict__ tlog)                // M target logits
{
    __shared__ __align__(16) unsigned short sA[128 * BK];
    __shared__ __align__(16) unsigned short sB[128 * BK];

    const int tid  = threadIdx.x;
    const int m0   = blockIdx.x * 128;
    const int v0   = blockIdx.y * 128;
    const int w    = tid >> 6;
    const int lane = tid & 63;
    const int wm   = w & 1;         // token half
    const int wn   = w >> 1;        // vocab half
    const int c    = lane & 15;
    const int q    = lane >> 4;

    floatx4 acc[4][4] = {};

    const int e0 = tid * 8;          // element offset per issue (8 bf16 = 16B)

    for (int kt = 0; kt < HDIM / BK; ++kt) {
        const int k0 = kt * BK;
#pragma unroll
        for (int it = 0; it < 4; ++it) {
            int e   = it * 2048 + e0;
            int row = e >> 6;        // /64
            int col = e & 63;
            async_copy16(Xb + (size_t)(m0 + row) * HDIM + (k0 + col), &sA[e]);
            async_copy16(Wb + (size_t)(v0 + row) * HDIM + (k0 + col), &sB[e]);
        }
        __syncthreads();
#pragma unroll
        for (int kk = 0; kk < BK; kk += 32) {
            short8 af[4], bf[4];
#pragma unroll
            for (int i = 0; i < 4; ++i)
                af[i] = *(const short8*)&sA[(wm * 64 + i * 16 + c) * BK + kk + q * 8];
#pragma unroll
            for (int j = 0; j < 4; ++j)
                bf[j] = *(const short8*)&sB[(wn * 64 + j * 16 + c) * BK + kk + q * 8];
#pragma unroll
            for (int i = 0; i < 4; ++i)
#pragma unroll
                for (int j = 0; j < 4; ++j)
                    acc[i][j] = __builtin_amdgcn_mfma_f32_16x16x32_bf16(
                        af[i], bf[j], acc[i][j], 0, 0, 0);
        }
        __syncthreads();
    }

    // Epilogue: C/D layout col = lane&15 (vocab), row = q*4+r (token)
    const int chunk = blockIdx.y * 2 + wn;   // 64-vocab chunk id
#pragma unroll
    for (int i = 0; i < 4; ++i) {
        float mx[4], sm[4];
#pragma unroll
        for (int r = 0; r < 4; ++r) {
            float m4 = acc[i][0][r];
            m4 = fmaxf(m4, acc[i][1][r]);
            m4 = fmaxf(m4, acc[i][2][r]);
            m4 = fmaxf(m4, acc[i][3][r]);
            mx[r] = m4;
        }
#pragma unroll
        for (int d = 1; d < 16; d <<= 1)
#pragma unroll
            for (int r = 0; r < 4; ++r)
                mx[r] = fmaxf(mx[r], __shfl_xor(mx[r], d, 64));
#pragma unroll
        for (int r = 0; r < 4; ++r) {
            float s = 0.f;
#pragma unroll
            for (int j = 0; j < 4; ++j) s += expf(acc[i][j][r] - mx[r]);
            sm[r] = s;
        }
#pragma unroll
        for (int d = 1; d < 16; d <<= 1)
#pragma unroll
            for (int r = 0; r < 4; ++r)
                sm[r] += __shfl_xor(sm[r], d, 64);

        const int tokenBase = m0 + wm * 64 + i * 16 + q * 4;
        if (c == 0) {
#pragma unroll
            for (int r = 0; r < 4; ++r) {
                pmax[(size_t)(tokenBase + r) * NCHUNK + chunk] = mx[r];
                psum[(size_t)(tokenBase + r) * NCHUNK + chunk] = sm[r];
            }
        }
        // target-logit capture
#pragma unroll
        for (int r = 0; r < 4; ++r) {
            int lab = y[tokenBase + r];
            int rel = lab - (v0 + wn * 64);
            if (rel >= 0 && rel < 64 && (rel & 15) == c)
                tlog[tokenBase + r] = acc[i][rel >> 4][r];
        }
    }
}

// --------------------------------------------- per-sequence avg target logp
// grid = BATCH, block = 256
__global__ __launch_bounds__(256) void finalize_kernel(
        const int* __restrict__ y,
        const float* __restrict__ pmax,
        const float* __restrict__ psum,
        const float* __restrict__ tlog,
        float* __restrict__ seqavg, int slot) {
    const int b   = blockIdx.x;
    const int tid = threadIdx.x;
    float lsum = 0.f;
    float lcnt = 0.f;
    for (int t = tid; t < TSEQ; t += 256) {
        int token = b * TSEQ + t;
        int lab = y[token];
        if (lab == IGNORE_INDEX) continue;
        const float* pm = &pmax[(size_t)token * NCHUNK];
        const float* ps = &psum[(size_t)token * NCHUNK];
        float m = -3.4e38f, s = 0.f;
        for (int c2 = 0; c2 < NCHUNK; ++c2) {
            float cm = pm[c2];
            float cs = ps[c2];
            if (cm > m) { s = s * expf(m - cm) + cs; m = cm; }
            else        { s += cs * expf(cm - m); }
        }
        float lse = m + logf(s);
        lsum += tlog[token] - lse;
        lcnt += 1.f;
    }
    __shared__ float rs[256];
    __shared__ float rc[256];
    rs[tid] = lsum; rc[tid] = lcnt;
    __syncthreads();
    for (int s2 = 128; s2 > 0; s2 >>= 1) {
        if (tid < s2) { rs[tid] += rs[tid + s2]; rc[tid] += rc[tid + s2]; }
        __syncthreads();
    }
    if (tid == 0) seqavg[slot * BATCH + b] = rs[0] / rc[0];
}

// ------------------------------------------------------------- final loss
__global__ void kto_loss_kernel(const float* __restrict__ seqavg,
                                const int* __restrict__ pref,
                                float* __restrict__ out) {
    if (threadIdx.x == 0 && blockIdx.x == 0) {
        float acc = 0.f;
        for (int b = 0; b < BATCH; ++b) {
            float lr   = seqavg[b] - seqavg[BATCH + b];
            float mult = pref[b] ? 1.f : -1.f;
            float z    = BETA * lr * mult;
            float sig  = 1.f / (1.f + expf(-z));
            acc += 1.f - sig;
        }
        out[0] = acc * (1.f / (float)BATCH);
    }
}

// ---------------------------------------------------------------- launcher
extern "C" void kernel_launch(void* const* d_in, const int* in_sizes, int n_in,
                              void* d_out, int out_size, void* d_ws, size_t ws_size,
                              hipStream_t stream) {
    const float* x      = (const float*)d_in[0];
    const float* ref_x  = (const float*)d_in[1];
    const int*   y      = (const int*)d_in[2];
    const int*   pref   = (const int*)d_in[3];
    const float* W      = (const float*)d_in[4];
    const float* ref_W  = (const float*)d_in[5];
    float* out = (float*)d_out;
    char*  ws  = (char*)d_ws;

    // workspace layout (bytes)
    const size_t WBF_OFF  = 0;                                   // 131,072,000
    const size_t XBF_OFF  = WBF_OFF + (size_t)VOCAB * HDIM * 2;  // + 8,388,608
    const size_t PMAX_OFF = XBF_OFF + (size_t)MTOK * HDIM * 2;   // + 4,096,000
    const size_t PSUM_OFF = PMAX_OFF + (size_t)MTOK * NCHUNK * 4;
    const size_t TLOG_OFF = PSUM_OFF + (size_t)MTOK * NCHUNK * 4;
    const size_t SEQ_OFF  = TLOG_OFF + (size_t)MTOK * 4;

    unsigned short* wbf  = (unsigned short*)(ws + WBF_OFF);
    unsigned short* xbf  = (unsigned short*)(ws + XBF_OFF);
    float* pmax   = (float*)(ws + PMAX_OFF);
    float* psum   = (float*)(ws + PSUM_OFF);
    float* tlog   = (float*)(ws + TLOG_OFF);
    float* seqavg = (float*)(ws + SEQ_OFF);

    for (int model = 0; model < 2; ++model) {
        const float* xin = model ? ref_x : x;
        const float* win = model ? ref_W : W;
        // W: 65,536,000 elts / 2048 per block = 32000 blocks
        cvt_bf16_kernel<<<VOCAB * HDIM / 2048, 256, 0, stream>>>(win, wbf);
        // x: 4,194,304 / 2048 = 2048 blocks
        cvt_bf16_kernel<<<MTOK * HDIM / 2048, 256, 0, stream>>>(xin, xbf);
        gemm_lse_kernel<<<dim3(MTOK / 128, VOCAB / 128), 256, 0, stream>>>(
            xbf, wbf, y, pmax, psum, tlog);
        finalize_kernel<<<BATCH, 256, 0, stream>>>(y, pmax, psum, tlog, seqavg, model);
    }
    kto_loss_kernel<<<1, 64, 0, stream>>>(seqavg, pref, out);
}

// Round 2
// 1108.361 us; speedup vs baseline: 7.1817x; 7.1817x over previous
//
#include <hip/hip_runtime.h>
#include <math.h>

// Problem constants (B=4, T=512, H=2048, V=32000)
#define BATCH 4
#define TSEQ 512
#define MTOK 2048          // B*T
#define HDIM 2048
#define VOCAB 32000
#define NCHUNK 500         // VOCAB / 64
#define IGNORE_INDEX (-100)
#define BETA 0.1f

typedef __attribute__((ext_vector_type(4))) float floatx4;
typedef __attribute__((ext_vector_type(8))) short short8;
typedef __attribute__((ext_vector_type(8))) unsigned short ushort8;

// ---------------------------------------------------------------- utilities
__device__ __forceinline__ unsigned short f2bf(float f) {
    unsigned int u = __float_as_uint(f);
    u += 0x7fffu + ((u >> 16) & 1u);   // RNE
    return (unsigned short)(u >> 16);
}

__device__ __forceinline__ void async_copy16(const unsigned short* g, unsigned short* l) {
    __builtin_amdgcn_global_load_lds(
        (const __attribute__((address_space(1))) void*)g,
        (__attribute__((address_space(3))) void*)l, 16, 0, 0);
}

// ------------------------------------------------------------ fp32 -> bf16
// grid = n/2048, block = 256, 8 elts/thread
__global__ __launch_bounds__(256) void cvt_bf16_kernel(
        const float* __restrict__ src, unsigned short* __restrict__ dst) {
    size_t i = (size_t)blockIdx.x * 256 + threadIdx.x;
    const floatx4* s = (const floatx4*)src + i * 2;
    floatx4 a = s[0];
    floatx4 b = s[1];
    ushort8 o;
    o[0] = f2bf(a[0]); o[1] = f2bf(a[1]); o[2] = f2bf(a[2]); o[3] = f2bf(a[3]);
    o[4] = f2bf(b[0]); o[5] = f2bf(b[1]); o[6] = f2bf(b[2]); o[7] = f2bf(b[3]);
    *((ushort8*)dst + i) = o;
}

// ------------------------------------------------------- GEMM + fused LSE
// C = Xb (M x H) * Wb^T (V x H)  -> per-token (max, sumexp) per 64-vocab chunk
// grid = (M/128, V/128), block = 256 (4 waves, each 64x64 via 4x4 MFMA 16x16x32)
// LDS layout is XOR-swizzled: global 16B-chunk g of row r sits at chunk
// position g^(r&7). Staging permutes the SOURCE address (dest must remain
// wave-uniform base + lane*16); fragment reads apply the matching XOR.
#define BK 64
__global__ __launch_bounds__(256, 2) void gemm_lse_kernel(
        const unsigned short* __restrict__ Xb,   // M x H bf16
        const unsigned short* __restrict__ Wb,   // V x H bf16
        const int* __restrict__ y,               // M labels
        float* __restrict__ pmax,                // M x NCHUNK
        float* __restrict__ psum,                // M x NCHUNK
        float* __restrict__ tlog)                // M target logits
{
    __shared__ __align__(16) unsigned short sA[128 * BK];
    __shared__ __align__(16) unsigned short sB[128 * BK];

    const int tid  = threadIdx.x;
    const int m0   = blockIdx.x * 128;
    const int v0   = blockIdx.y * 128;
    const int w    = tid >> 6;
    const int lane = tid & 63;
    const int wm   = w & 1;         // token half
    const int wn   = w >> 1;        // vocab half
    const int c    = lane & 15;
    const int q    = lane >> 4;

    floatx4 acc[4][4] = {};

    // staging: LDS elt offset e (lane-contiguous), swizzled global source col
    const int e0 = tid * 8;

    for (int kt = 0; kt < HDIM / BK; ++kt) {
        const int k0 = kt * BK;
#pragma unroll
        for (int it = 0; it < 4; ++it) {
            int e   = it * 2048 + e0;
            int row = e >> 6;                    // 0..127
            int p   = (e >> 3) & 7;              // LDS chunk position
            int col = (p ^ (row & 7)) * 8;       // swizzled global chunk
            async_copy16(Xb + (size_t)(m0 + row) * HDIM + (k0 + col), &sA[e]);
            async_copy16(Wb + (size_t)(v0 + row) * HDIM + (k0 + col), &sB[e]);
        }
        __syncthreads();
#pragma unroll
        for (int kk = 0; kk < BK; kk += 32) {
            short8 af[4], bf[4];
            const int gq = (kk >> 3) + q;        // wanted global chunk 0..7
            const int pq = gq ^ (c & 7);         // its swizzled LDS position
#pragma unroll
            for (int i = 0; i < 4; ++i)
                af[i] = *(const short8*)&sA[(wm * 64 + i * 16 + c) * BK + pq * 8];
#pragma unroll
            for (int j = 0; j < 4; ++j)
                bf[j] = *(const short8*)&sB[(wn * 64 + j * 16 + c) * BK + pq * 8];
#pragma unroll
            for (int i = 0; i < 4; ++i)
#pragma unroll
                for (int j = 0; j < 4; ++j)
                    acc[i][j] = __builtin_amdgcn_mfma_f32_16x16x32_bf16(
                        af[i], bf[j], acc[i][j], 0, 0, 0);
        }
        __syncthreads();
    }

    // Epilogue: C/D layout col = lane&15 (vocab), row = q*4+r (token)
    const int chunk = blockIdx.y * 2 + wn;   // 64-vocab chunk id
#pragma unroll
    for (int i = 0; i < 4; ++i) {
        float mx[4], sm[4];
#pragma unroll
        for (int r = 0; r < 4; ++r) {
            float m4 = acc[i][0][r];
            m4 = fmaxf(m4, acc[i][1][r]);
            m4 = fmaxf(m4, acc[i][2][r]);
            m4 = fmaxf(m4, acc[i][3][r]);
            mx[r] = m4;
        }
#pragma unroll
        for (int d = 1; d < 16; d <<= 1)
#pragma unroll
            for (int r = 0; r < 4; ++r)
                mx[r] = fmaxf(mx[r], __shfl_xor(mx[r], d, 64));
#pragma unroll
        for (int r = 0; r < 4; ++r) {
            float s = 0.f;
#pragma unroll
            for (int j = 0; j < 4; ++j) s += expf(acc[i][j][r] - mx[r]);
            sm[r] = s;
        }
#pragma unroll
        for (int d = 1; d < 16; d <<= 1)
#pragma unroll
            for (int r = 0; r < 4; ++r)
                sm[r] += __shfl_xor(sm[r], d, 64);

        const int tokenBase = m0 + wm * 64 + i * 16 + q * 4;
        if (c == 0) {
#pragma unroll
            for (int r = 0; r < 4; ++r) {
                pmax[(size_t)(tokenBase + r) * NCHUNK + chunk] = mx[r];
                psum[(size_t)(tokenBase + r) * NCHUNK + chunk] = sm[r];
            }
        }
        // target-logit capture — LITERAL j index only (runtime index into acc
        // demotes the accumulator to scratch: R1's 12 GB WRITE_SIZE bug)
#pragma unroll
        for (int r = 0; r < 4; ++r) {
            int lab = y[tokenBase + r];
            int rel = lab - (v0 + wn * 64);
            if (rel >= 0 && rel < 64 && (rel & 15) == c) {
#pragma unroll
                for (int j = 0; j < 4; ++j)
                    if ((rel >> 4) == j)
                        tlog[tokenBase + r] = acc[i][j][r];
            }
        }
    }
}

// --------------------------------------------- per-token logp (wave/token)
// grid = MTOK/4, block = 256 (4 waves, one token each)
__global__ __launch_bounds__(256) void finalize_kernel(
        const int* __restrict__ y,
        const float* __restrict__ pmax,
        const float* __restrict__ psum,
        const float* __restrict__ tlog,
        float* __restrict__ tokll, int slot) {
    const int wv    = threadIdx.x >> 6;
    const int lane  = threadIdx.x & 63;
    const int token = blockIdx.x * 4 + wv;

    const float* pm = &pmax[(size_t)token * NCHUNK];
    const float* ps = &psum[(size_t)token * NCHUNK];
    float m = -3.4e38f, s = 0.f;
    for (int c2 = lane; c2 < NCHUNK; c2 += 64) {
        float cm = pm[c2];
        float cs = ps[c2];
        if (cm > m) { s = s * expf(m - cm) + cs; m = cm; }
        else        { s += cs * expf(cm - m); }
    }
#pragma unroll
    for (int d = 1; d < 64; d <<= 1) {
        float om = __shfl_xor(m, d, 64);
        float os = __shfl_xor(s, d, 64);
        if (om > m) { s = s * expf(m - om) + os; m = om; }
        else        { s += os * expf(om - m); }
    }
    if (lane == 0) {
        int lab = y[token];
        float lse = m + logf(s);
        tokll[(size_t)slot * MTOK + token] =
            (lab == IGNORE_INDEX) ? 0.f : (tlog[token] - lse);
    }
}

// --------------------------------------------- per-sequence average logp
// grid = 8 (slot*4 + b), block = 256
__global__ __launch_bounds__(256) void seqreduce_kernel(
        const int* __restrict__ y,
        const float* __restrict__ tokll,
        float* __restrict__ seqavg) {
    const int slot = blockIdx.x >> 2;
    const int b    = blockIdx.x & 3;
    const int tid  = threadIdx.x;
    float lsum = 0.f, lcnt = 0.f;
    for (int t = tid; t < TSEQ; t += 256) {
        int token = b * TSEQ + t;
        lsum += tokll[(size_t)slot * MTOK + token];
        lcnt += (y[token] != IGNORE_INDEX) ? 1.f : 0.f;
    }
    __shared__ float rs[256];
    __shared__ float rc[256];
    rs[tid] = lsum; rc[tid] = lcnt;
    __syncthreads();
    for (int s2 = 128; s2 > 0; s2 >>= 1) {
        if (tid < s2) { rs[tid] += rs[tid + s2]; rc[tid] += rc[tid + s2]; }
        __syncthreads();
    }
    if (tid == 0) seqavg[slot * BATCH + b] = rs[0] / rc[0];
}

// ------------------------------------------------------------- final loss
__global__ void kto_loss_kernel(const float* __restrict__ seqavg,
                                const int* __restrict__ pref,
                                float* __restrict__ out) {
    if (threadIdx.x == 0 && blockIdx.x == 0) {
        float acc = 0.f;
        for (int b = 0; b < BATCH; ++b) {
            float lr   = seqavg[b] - seqavg[BATCH + b];
            float mult = pref[b] ? 1.f : -1.f;
            float z    = BETA * lr * mult;
            float sig  = 1.f / (1.f + expf(-z));
            acc += 1.f - sig;
        }
        out[0] = acc * (1.f / (float)BATCH);
    }
}

// ---------------------------------------------------------------- launcher
extern "C" void kernel_launch(void* const* d_in, const int* in_sizes, int n_in,
                              void* d_out, int out_size, void* d_ws, size_t ws_size,
                              hipStream_t stream) {
    const float* x      = (const float*)d_in[0];
    const float* ref_x  = (const float*)d_in[1];
    const int*   y      = (const int*)d_in[2];
    const int*   pref   = (const int*)d_in[3];
    const float* W      = (const float*)d_in[4];
    const float* ref_W  = (const float*)d_in[5];
    float* out = (float*)d_out;
    char*  ws  = (char*)d_ws;

    // workspace layout (bytes)
    const size_t WBF_OFF  = 0;                                   // 131,072,000
    const size_t XBF_OFF  = WBF_OFF + (size_t)VOCAB * HDIM * 2;  // + 8,388,608
    const size_t PMAX_OFF = XBF_OFF + (size_t)MTOK * HDIM * 2;   // + 4,096,000
    const size_t PSUM_OFF = PMAX_OFF + (size_t)MTOK * NCHUNK * 4;
    const size_t TLOG_OFF = PSUM_OFF + (size_t)MTOK * NCHUNK * 4;
    const size_t TOKL_OFF = TLOG_OFF + (size_t)MTOK * 4;         // 2 slots
    const size_t SEQ_OFF  = TOKL_OFF + (size_t)2 * MTOK * 4;

    unsigned short* wbf  = (unsigned short*)(ws + WBF_OFF);
    unsigned short* xbf  = (unsigned short*)(ws + XBF_OFF);
    float* pmax   = (float*)(ws + PMAX_OFF);
    float* psum   = (float*)(ws + PSUM_OFF);
    float* tlog   = (float*)(ws + TLOG_OFF);
    float* tokll  = (float*)(ws + TOKL_OFF);
    float* seqavg = (float*)(ws + SEQ_OFF);

    for (int model = 0; model < 2; ++model) {
        const float* xin = model ? ref_x : x;
        const float* win = model ? ref_W : W;
        cvt_bf16_kernel<<<VOCAB * HDIM / 2048, 256, 0, stream>>>(win, wbf);
        cvt_bf16_kernel<<<MTOK * HDIM / 2048, 256, 0, stream>>>(xin, xbf);
        gemm_lse_kernel<<<dim3(MTOK / 128, VOCAB / 128), 256, 0, stream>>>(
            xbf, wbf, y, pmax, psum, tlog);
        finalize_kernel<<<MTOK / 4, 256, 0, stream>>>(y, pmax, psum, tlog, tokll, model);
    }
    seqreduce_kernel<<<8, 256, 0, stream>>>(y, tokll, seqavg);
    kto_loss_kernel<<<1, 64, 0, stream>>>(seqavg, pref, out);
}

// Round 3
// 1104.268 us; speedup vs baseline: 7.2083x; 1.0037x over previous
//
#include <hip/hip_runtime.h>
#include <math.h>

// Problem constants (B=4, T=512, H=2048, V=32000)
#define BATCH 4
#define TSEQ 512
#define MTOK 2048          // B*T
#define HDIM 2048
#define VOCAB 32000
#define NCHUNK 500         // VOCAB / 64
#define IGNORE_INDEX (-100)
#define BETA 0.1f

#define WBLK (VOCAB * HDIM / 2048)   // 32000 blocks per W convert
#define XBLK (MTOK * HDIM / 2048)    // 2048 blocks per x convert

typedef __attribute__((ext_vector_type(4))) float floatx4;
typedef __attribute__((ext_vector_type(8))) short short8;
typedef __attribute__((ext_vector_type(8))) unsigned short ushort8;

// ---------------------------------------------------------------- utilities
__device__ __forceinline__ unsigned short f2bf(float f) {
    unsigned int u = __float_as_uint(f);
    u += 0x7fffu + ((u >> 16) & 1u);   // RNE
    return (unsigned short)(u >> 16);
}

__device__ __forceinline__ void async_copy16(const unsigned short* g, unsigned short* l) {
    __builtin_amdgcn_global_load_lds(
        (const __attribute__((address_space(1))) void*)g,
        (__attribute__((address_space(3))) void*)l, 16, 0, 0);
}

__device__ __forceinline__ void cvt_block(const float* __restrict__ src,
                                          unsigned short* __restrict__ dst,
                                          size_t i) {
    const floatx4* s = (const floatx4*)src + i * 2;
    floatx4 a = s[0];
    floatx4 b = s[1];
    ushort8 o;
    o[0] = f2bf(a[0]); o[1] = f2bf(a[1]); o[2] = f2bf(a[2]); o[3] = f2bf(a[3]);
    o[4] = f2bf(b[0]); o[5] = f2bf(b[1]); o[6] = f2bf(b[2]); o[7] = f2bf(b[3]);
    *((ushort8*)dst + i) = o;
}

// ------------------------------------------------ fp32 -> bf16, one tensor
__global__ __launch_bounds__(256) void cvt_bf16_kernel(
        const float* __restrict__ src, unsigned short* __restrict__ dst) {
    cvt_block(src, dst, (size_t)blockIdx.x * 256 + threadIdx.x);
}

// --------------------------------------------- fp32 -> bf16, all 4 tensors
// grid = 2*WBLK + 2*XBLK = 68096 blocks
__global__ __launch_bounds__(256) void cvt_all_kernel(
        const float* __restrict__ s0, const float* __restrict__ s1,
        const float* __restrict__ s2, const float* __restrict__ s3,
        unsigned short* __restrict__ d0, unsigned short* __restrict__ d1,
        unsigned short* __restrict__ d2, unsigned short* __restrict__ d3) {
    int b = blockIdx.x;
    const float* src;
    unsigned short* dst;
    int rel;
    if (b < WBLK)              { src = s0; dst = d0; rel = b; }
    else if (b < 2 * WBLK)     { src = s1; dst = d1; rel = b - WBLK; }
    else if (b < 2*WBLK + XBLK){ src = s2; dst = d2; rel = b - 2*WBLK; }
    else                       { src = s3; dst = d3; rel = b - 2*WBLK - XBLK; }
    cvt_block(src, dst, (size_t)rel * 256 + threadIdx.x);
}

// ------------------------------------------------------- GEMM + fused LSE
// C = Xb (M x H) * Wb^T (V x H)  -> per-token (max, sumexp) per 64-vocab chunk
// grid = (M/128, V/128, nmodels), block = 256 (4 waves, each 64x64)
// LDS layout is XOR-swizzled: global 16B-chunk g of row r sits at chunk
// position g^(r&7); staging permutes the SOURCE address (global_load_lds dest
// must remain wave-uniform base + lane*16); reads apply the matching XOR.
#define BK 64
__global__ __launch_bounds__(256, 2) void gemm_lse_kernel(
        const unsigned short* __restrict__ Xb0,
        const unsigned short* __restrict__ Xb1,
        const unsigned short* __restrict__ Wb0,
        const unsigned short* __restrict__ Wb1,
        const int* __restrict__ y,               // M labels
        float* __restrict__ pmax,                // [slot][M][NCHUNK]
        float* __restrict__ psum,                // [slot][M][NCHUNK]
        float* __restrict__ tlog,                // [slot][M]
        int slot_base)
{
    __shared__ __align__(16) unsigned short sA[128 * BK];
    __shared__ __align__(16) unsigned short sB[128 * BK];

    const int slot = slot_base + blockIdx.z;
    const unsigned short* __restrict__ Xb = slot ? Xb1 : Xb0;
    const unsigned short* __restrict__ Wb = slot ? Wb1 : Wb0;

    const int tid  = threadIdx.x;
    const int m0   = blockIdx.x * 128;
    const int v0   = blockIdx.y * 128;
    const int w    = tid >> 6;
    const int lane = tid & 63;
    const int wm   = w & 1;         // token half
    const int wn   = w >> 1;        // vocab half
    const int c    = lane & 15;
    const int q    = lane >> 4;

    floatx4 acc[4][4] = {};

    const int e0 = tid * 8;

    for (int kt = 0; kt < HDIM / BK; ++kt) {
        const int k0 = kt * BK;
#pragma unroll
        for (int it = 0; it < 4; ++it) {
            int e   = it * 2048 + e0;
            int row = e >> 6;                    // 0..127
            int p   = (e >> 3) & 7;              // LDS chunk position
            int col = (p ^ (row & 7)) * 8;       // swizzled global chunk
            async_copy16(Xb + (size_t)(m0 + row) * HDIM + (k0 + col), &sA[e]);
            async_copy16(Wb + (size_t)(v0 + row) * HDIM + (k0 + col), &sB[e]);
        }
        __syncthreads();
#pragma unroll
        for (int kk = 0; kk < BK; kk += 32) {
            short8 af[4], bf[4];
            const int gq = (kk >> 3) + q;        // wanted global chunk 0..7
            const int pq = gq ^ (c & 7);         // its swizzled LDS position
#pragma unroll
            for (int i = 0; i < 4; ++i)
                af[i] = *(const short8*)&sA[(wm * 64 + i * 16 + c) * BK + pq * 8];
#pragma unroll
            for (int j = 0; j < 4; ++j)
                bf[j] = *(const short8*)&sB[(wn * 64 + j * 16 + c) * BK + pq * 8];
#pragma unroll
            for (int i = 0; i < 4; ++i)
#pragma unroll
                for (int j = 0; j < 4; ++j)
                    acc[i][j] = __builtin_amdgcn_mfma_f32_16x16x32_bf16(
                        af[i], bf[j], acc[i][j], 0, 0, 0);
        }
        __syncthreads();
    }

    // Epilogue: C/D layout col = lane&15 (vocab), row = q*4+r (token)
    const int chunk = blockIdx.y * 2 + wn;   // 64-vocab chunk id
#pragma unroll
    for (int i = 0; i < 4; ++i) {
        float mx[4], sm[4];
#pragma unroll
        for (int r = 0; r < 4; ++r) {
            float m4 = acc[i][0][r];
            m4 = fmaxf(m4, acc[i][1][r]);
            m4 = fmaxf(m4, acc[i][2][r]);
            m4 = fmaxf(m4, acc[i][3][r]);
            mx[r] = m4;
        }
#pragma unroll
        for (int d = 1; d < 16; d <<= 1)
#pragma unroll
            for (int r = 0; r < 4; ++r)
                mx[r] = fmaxf(mx[r], __shfl_xor(mx[r], d, 64));
#pragma unroll
        for (int r = 0; r < 4; ++r) {
            float s = 0.f;
#pragma unroll
            for (int j = 0; j < 4; ++j) s += expf(acc[i][j][r] - mx[r]);
            sm[r] = s;
        }
#pragma unroll
        for (int d = 1; d < 16; d <<= 1)
#pragma unroll
            for (int r = 0; r < 4; ++r)
                sm[r] += __shfl_xor(sm[r], d, 64);

        const int tokenBase = m0 + wm * 64 + i * 16 + q * 4;
        if (c == 0) {
#pragma unroll
            for (int r = 0; r < 4; ++r) {
                pmax[(size_t)(slot * MTOK + tokenBase + r) * NCHUNK + chunk] = mx[r];
                psum[(size_t)(slot * MTOK + tokenBase + r) * NCHUNK + chunk] = sm[r];
            }
        }
        // target-logit capture — LITERAL j index only (runtime index into acc
        // demotes the accumulator to scratch: R1's 12 GB WRITE_SIZE bug)
#pragma unroll
        for (int r = 0; r < 4; ++r) {
            int lab = y[tokenBase + r];
            int rel = lab - (v0 + wn * 64);
            if (rel >= 0 && rel < 64 && (rel & 15) == c) {
#pragma unroll
                for (int j = 0; j < 4; ++j)
                    if ((rel >> 4) == j)
                        tlog[(size_t)slot * MTOK + tokenBase + r] = acc[i][j][r];
            }
        }
    }
}

// --------------------------------------------- per-token logp (wave/token)
// grid = (MTOK/4, nmodels), block = 256 (4 waves, one token each)
__global__ __launch_bounds__(256) void finalize_kernel(
        const int* __restrict__ y,
        const float* __restrict__ pmax,
        const float* __restrict__ psum,
        const float* __restrict__ tlog,
        float* __restrict__ tokll, int slot_base) {
    const int wv    = threadIdx.x >> 6;
    const int lane  = threadIdx.x & 63;
    const int token = blockIdx.x * 4 + wv;
    const int slot  = slot_base + blockIdx.y;

    const float* pm = &pmax[(size_t)(slot * MTOK + token) * NCHUNK];
    const float* ps = &psum[(size_t)(slot * MTOK + token) * NCHUNK];
    float m = -3.4e38f, s = 0.f;
    for (int c2 = lane; c2 < NCHUNK; c2 += 64) {
        float cm = pm[c2];
        float cs = ps[c2];
        if (cm > m) { s = s * expf(m - cm) + cs; m = cm; }
        else        { s += cs * expf(cm - m); }
    }
#pragma unroll
    for (int d = 1; d < 64; d <<= 1) {
        float om = __shfl_xor(m, d, 64);
        float os = __shfl_xor(s, d, 64);
        if (om > m) { s = s * expf(m - om) + os; m = om; }
        else        { s += os * expf(om - m); }
    }
    if (lane == 0) {
        int lab = y[token];
        float lse = m + logf(s);
        tokll[(size_t)slot * MTOK + token] =
            (lab == IGNORE_INDEX) ? 0.f : (tlog[(size_t)slot * MTOK + token] - lse);
    }
}

// ---------------------------------- fused seq-average + KTO loss, 1 block
__global__ __launch_bounds__(256) void tail_kernel(
        const int* __restrict__ y,
        const float* __restrict__ tokll,
        const int* __restrict__ pref,
        float* __restrict__ out) {
    __shared__ float rs[256];
    __shared__ float rc[256];
    __shared__ float seqavg[8];
    const int tid = threadIdx.x;
    for (int sb = 0; sb < 8; ++sb) {
        const int slot = sb >> 2;
        const int b    = sb & 3;
        float lsum = 0.f, lcnt = 0.f;
        for (int t = tid; t < TSEQ; t += 256) {
            int token = b * TSEQ + t;
            lsum += tokll[(size_t)slot * MTOK + token];
            lcnt += (y[token] != IGNORE_INDEX) ? 1.f : 0.f;
        }
        rs[tid] = lsum; rc[tid] = lcnt;
        __syncthreads();
        for (int s2 = 128; s2 > 0; s2 >>= 1) {
            if (tid < s2) { rs[tid] += rs[tid + s2]; rc[tid] += rc[tid + s2]; }
            __syncthreads();
        }
        if (tid == 0) seqavg[sb] = rs[0] / rc[0];
        __syncthreads();
    }
    if (tid == 0) {
        float acc = 0.f;
        for (int b = 0; b < BATCH; ++b) {
            float lr   = seqavg[b] - seqavg[BATCH + b];
            float mult = pref[b] ? 1.f : -1.f;
            float z    = BETA * lr * mult;
            float sig  = 1.f / (1.f + expf(-z));
            acc += 1.f - sig;
        }
        out[0] = acc * (1.f / (float)BATCH);
    }
}

// ---------------------------------------------------------------- launcher
extern "C" void kernel_launch(void* const* d_in, const int* in_sizes, int n_in,
                              void* d_out, int out_size, void* d_ws, size_t ws_size,
                              hipStream_t stream) {
    const float* x      = (const float*)d_in[0];
    const float* ref_x  = (const float*)d_in[1];
    const int*   y      = (const int*)d_in[2];
    const int*   pref   = (const int*)d_in[3];
    const float* W      = (const float*)d_in[4];
    const float* ref_W  = (const float*)d_in[5];
    float* out = (float*)d_out;
    char*  ws  = (char*)d_ws;

    const size_t WSZ = (size_t)VOCAB * HDIM * 2;   // 131,072,000 B
    const size_t XSZ = (size_t)MTOK * HDIM * 2;    //   8,388,608 B
    const size_t PSZ = (size_t)2 * MTOK * NCHUNK * 4;  // dual-slot pmax/psum

    // dual-buffer layout needs ~295.3 MB; ws_size is a host constant, so this
    // branch is identical every call (graph-safe).
    const size_t need_dual = 2*WSZ + 2*XSZ + 2*PSZ + (size_t)4*MTOK*4 + 4096;

    if (ws_size >= need_dual) {
        unsigned short* wbf0 = (unsigned short*)(ws);
        unsigned short* wbf1 = (unsigned short*)(ws + WSZ);
        unsigned short* xbf0 = (unsigned short*)(ws + 2*WSZ);
        unsigned short* xbf1 = (unsigned short*)(ws + 2*WSZ + XSZ);
        float* pmax  = (float*)(ws + 2*WSZ + 2*XSZ);
        float* psum  = (float*)(ws + 2*WSZ + 2*XSZ + PSZ);
        float* tlog  = (float*)(ws + 2*WSZ + 2*XSZ + 2*PSZ);
        float* tokll = (float*)(ws + 2*WSZ + 2*XSZ + 2*PSZ + (size_t)2*MTOK*4);

        cvt_all_kernel<<<2*WBLK + 2*XBLK, 256, 0, stream>>>(
            W, ref_W, x, ref_x, wbf0, wbf1, xbf0, xbf1);
        gemm_lse_kernel<<<dim3(MTOK/128, VOCAB/128, 2), 256, 0, stream>>>(
            xbf0, xbf1, wbf0, wbf1, y, pmax, psum, tlog, 0);
        finalize_kernel<<<dim3(MTOK/4, 2), 256, 0, stream>>>(
            y, pmax, psum, tlog, tokll, 0);
        tail_kernel<<<1, 256, 0, stream>>>(y, tokll, pref, out);
    } else {
        // serial fallback (R2 structure): single W/X buffer reused per model
        unsigned short* wbf = (unsigned short*)(ws);
        unsigned short* xbf = (unsigned short*)(ws + WSZ);
        float* pmax  = (float*)(ws + WSZ + XSZ);
        float* psum  = (float*)(ws + WSZ + XSZ + PSZ);
        float* tlog  = (float*)(ws + WSZ + XSZ + 2*PSZ);
        float* tokll = (float*)(ws + WSZ + XSZ + 2*PSZ + (size_t)2*MTOK*4);

        for (int model = 0; model < 2; ++model) {
            const float* xin = model ? ref_x : x;
            const float* win = model ? ref_W : W;
            cvt_bf16_kernel<<<WBLK, 256, 0, stream>>>(win, wbf);
            cvt_bf16_kernel<<<XBLK, 256, 0, stream>>>(xin, xbf);
            gemm_lse_kernel<<<dim3(MTOK/128, VOCAB/128, 1), 256, 0, stream>>>(
                xbf, xbf, wbf, wbf, y, pmax, psum, tlog, model);
            finalize_kernel<<<dim3(MTOK/4, 1), 256, 0, stream>>>(
                y, pmax, psum, tlog, tokll, model);
        }
        tail_kernel<<<1, 256, 0, stream>>>(y, tokll, pref, out);
    }
}